// Round 6
// baseline (273.683 us; speedup 1.0000x reference)
//
#include <hip/hip_runtime.h>

// DLRM interact_features, B=1, D=16777216, 4 features (x, ly_0, ly_1, ly_2).
// out[0..D-1] = x (done via SDMA hipMemcpyAsync);
// out[D..D+5] = [x.l0, x.l1, l0.l1, x.l2, l0.l2, l1.l2]
// Round 5 change: kernel is PURE-READ (no interleaved stores) — R4 showed the
// fused load+store version is latency-bound at 22% HBM, not BW-bound.

typedef float fvec4 __attribute__((ext_vector_type(4)));

constexpr int D_TOTAL = 16777216;
constexpr int NVEC    = D_TOTAL / 4;           // fvec4 elements = 4194304
constexpr int BLOCK   = 256;
constexpr int GRID    = 2048;
constexpr int ITERS   = NVEC / (BLOCK * GRID); // exactly 8
static_assert(NVEC == BLOCK * GRID * ITERS, "exact tiling");

#define FMA4(acc, u, v) \
    acc += u.x * v.x + u.y * v.y + u.z * v.z + u.w * v.w;

__global__ __launch_bounds__(BLOCK) void dlrm_dot(
        const fvec4* __restrict__ x,
        const fvec4* __restrict__ l0,
        const fvec4* __restrict__ l1,
        const fvec4* __restrict__ l2,
        float* __restrict__ partials)  // [6][GRID]
{
    float s[6] = {0.f, 0.f, 0.f, 0.f, 0.f, 0.f};

    const int base   = blockIdx.x * BLOCK + threadIdx.x;
    const int stride = BLOCK * GRID;

    // Compile-time trip count, 2-way unroll: 8 pure loads in flight, no
    // stores in the loop (copy is handled by SDMA memcpy).
    #pragma unroll 2
    for (int it = 0; it < ITERS; ++it) {
        const int i = base + it * stride;
        const fvec4 a = x[i];
        const fvec4 b = l0[i];
        const fvec4 c = l1[i];
        const fvec4 d = l2[i];
        FMA4(s[0], a, b)   // x  . l0
        FMA4(s[1], a, c)   // x  . l1
        FMA4(s[2], b, c)   // l0 . l1
        FMA4(s[3], a, d)   // x  . l2
        FMA4(s[4], b, d)   // l0 . l2
        FMA4(s[5], c, d)   // l1 . l2
    }

    // wave-64 butterfly reduction of all 6 partials
    #pragma unroll
    for (int off = 32; off > 0; off >>= 1) {
        #pragma unroll
        for (int k = 0; k < 6; ++k)
            s[k] += __shfl_down(s[k], off, 64);
    }

    // cross-wave reduction via LDS (4 waves), one plain store per pair per
    // block into partials (no atomics).
    __shared__ float red[BLOCK / 64][6];
    const int wave = threadIdx.x >> 6;
    const int lane = threadIdx.x & 63;
    if (lane == 0) {
        #pragma unroll
        for (int k = 0; k < 6; ++k) red[wave][k] = s[k];
    }
    __syncthreads();

    if (threadIdx.x < 6) {
        float tot = 0.f;
        #pragma unroll
        for (int w = 0; w < BLOCK / 64; ++w) tot += red[w][threadIdx.x];
        partials[threadIdx.x * GRID + blockIdx.x] = tot;
    }
}

// 6 waves, wave k sums partials[k][0..GRID) and writes out_pairs[k].
__global__ __launch_bounds__(384) void dlrm_reduce(
        const float* __restrict__ partials, float* __restrict__ out_pairs)
{
    const int w    = threadIdx.x >> 6;
    const int lane = threadIdx.x & 63;
    const float* row = partials + w * GRID;
    float s = 0.f;
    #pragma unroll
    for (int i = 0; i < GRID / 64; ++i) s += row[lane + i * 64];
    #pragma unroll
    for (int off = 32; off > 0; off >>= 1) s += __shfl_down(s, off, 64);
    if (lane == 0) out_pairs[w] = s;
}

// ---- fallback path (ws too small): atomic version, still pure-read ----
__global__ void dlrm_init_pairs(float* __restrict__ out) {
    if (threadIdx.x < 6) out[(size_t)D_TOTAL + threadIdx.x] = 0.0f;
}

__global__ __launch_bounds__(BLOCK) void dlrm_dot_atomic(
        const fvec4* __restrict__ x, const fvec4* __restrict__ l0,
        const fvec4* __restrict__ l1, const fvec4* __restrict__ l2,
        float* __restrict__ out_pairs)
{
    float s[6] = {0.f, 0.f, 0.f, 0.f, 0.f, 0.f};
    const int base = blockIdx.x * BLOCK + threadIdx.x;
    const int stride = BLOCK * GRID;
    #pragma unroll 2
    for (int it = 0; it < ITERS; ++it) {
        const int i = base + it * stride;
        const fvec4 a = x[i], b = l0[i], c = l1[i], d = l2[i];
        FMA4(s[0], a, b) FMA4(s[1], a, c) FMA4(s[2], b, c)
        FMA4(s[3], a, d) FMA4(s[4], b, d) FMA4(s[5], c, d)
    }
    #pragma unroll
    for (int off = 32; off > 0; off >>= 1)
        #pragma unroll
        for (int k = 0; k < 6; ++k) s[k] += __shfl_down(s[k], off, 64);
    __shared__ float red[BLOCK / 64][6];
    const int wave = threadIdx.x >> 6, lane = threadIdx.x & 63;
    if (lane == 0)
        for (int k = 0; k < 6; ++k) red[wave][k] = s[k];
    __syncthreads();
    if (threadIdx.x < 6) {
        float tot = 0.f;
        for (int w = 0; w < BLOCK / 64; ++w) tot += red[w][threadIdx.x];
        atomicAdd(out_pairs + threadIdx.x, tot);
    }
}

extern "C" void kernel_launch(void* const* d_in, const int* in_sizes, int n_in,
                              void* d_out, int out_size, void* d_ws, size_t ws_size,
                              hipStream_t stream) {
    const fvec4* x  = (const fvec4*)d_in[0];
    const fvec4* l0 = (const fvec4*)d_in[1];
    const fvec4* l1 = (const fvec4*)d_in[2];
    const fvec4* l2 = (const fvec4*)d_in[3];
    float* out = (float*)d_out;

    if (ws_size >= (size_t)6 * GRID * sizeof(float)) {
        float* partials = (float*)d_ws;
        dlrm_dot<<<GRID, BLOCK, 0, stream>>>(x, l0, l1, l2, partials);
        dlrm_reduce<<<1, 384, 0, stream>>>(partials, out + (size_t)D_TOTAL);
    } else {
        dlrm_init_pairs<<<1, 64, 0, stream>>>(out);
        dlrm_dot_atomic<<<GRID, BLOCK, 0, stream>>>(
            x, l0, l1, l2, out + (size_t)D_TOTAL);
    }
    // x -> out[0..D) copy on the SDMA engine (sanctioned d2d async copy);
    // no CU store traffic, no load->store vmcnt chains in the dot kernel.
    hipMemcpyAsync(out, x, (size_t)D_TOTAL * sizeof(float),
                   hipMemcpyDeviceToDevice, stream);
}

// Round 8
// 269.723 us; speedup vs baseline: 1.0147x; 1.0147x over previous
//
#include <hip/hip_runtime.h>

// DLRM interact_features, B=1, D=16777216, 4 features (x, ly_0, ly_1, ly_2).
// out[0..D-1] = x (fused store);  out[D..D+5] = strict-lower-tri dots.
// Round 7: CONTIGUOUS per-block chunks (no 8MB grid-stride jumps) to fix the
// read-supply ceiling (~2.6 TB/s) seen in R1/R4/R6 regardless of structure.
// Copy fused back on the CU (SDMA memcpy measured ~0.8 TB/s, regressed R6).

typedef float fvec4 __attribute__((ext_vector_type(4)));

constexpr int D_TOTAL = 16777216;
constexpr int NVEC    = D_TOTAL / 4;     // 4194304 fvec4
constexpr int BLOCK   = 256;
constexpr int GRID    = 2048;
constexpr int CHUNK   = NVEC / GRID;     // 2048 fvec4 = 32KB contiguous per array
constexpr int ITERS   = CHUNK / BLOCK;   // 8
static_assert(NVEC == GRID * CHUNK && CHUNK == BLOCK * ITERS, "exact tiling");

#define FMA4(acc, u, v) \
    acc += u.x * v.x + u.y * v.y + u.z * v.z + u.w * v.w;

__global__ __launch_bounds__(BLOCK) void dlrm_interact_main(
        const fvec4* __restrict__ x,
        const fvec4* __restrict__ l0,
        const fvec4* __restrict__ l1,
        const fvec4* __restrict__ l2,
        fvec4* __restrict__ out_copy,
        float* __restrict__ partials)  // [6][GRID]
{
    float s[6] = {0.f, 0.f, 0.f, 0.f, 0.f, 0.f};

    // Contiguous: block b reads [b*CHUNK, (b+1)*CHUNK) from each array,
    // advancing 4KB per iteration. Sequential pages, prefetch-friendly.
    const int base = blockIdx.x * CHUNK + threadIdx.x;

    #pragma unroll 4
    for (int it = 0; it < ITERS; ++it) {
        const int i = base + it * BLOCK;
        const fvec4 a = x[i];
        const fvec4 b = l0[i];
        const fvec4 c = l1[i];
        const fvec4 d = l2[i];
        __builtin_nontemporal_store(a, &out_copy[i]);
        FMA4(s[0], a, b)   // x  . l0
        FMA4(s[1], a, c)   // x  . l1
        FMA4(s[2], b, c)   // l0 . l1
        FMA4(s[3], a, d)   // x  . l2
        FMA4(s[4], b, d)   // l0 . l2
        FMA4(s[5], c, d)   // l1 . l2
    }

    // wave-64 butterfly reduction of all 6 partials
    #pragma unroll
    for (int off = 32; off > 0; off >>= 1) {
        #pragma unroll
        for (int k = 0; k < 6; ++k)
            s[k] += __shfl_down(s[k], off, 64);
    }

    // cross-wave reduction via LDS (4 waves), one plain store per pair per
    // block (no atomics).
    __shared__ float red[BLOCK / 64][6];
    const int wave = threadIdx.x >> 6;
    const int lane = threadIdx.x & 63;
    if (lane == 0) {
        #pragma unroll
        for (int k = 0; k < 6; ++k) red[wave][k] = s[k];
    }
    __syncthreads();

    if (threadIdx.x < 6) {
        float tot = 0.f;
        #pragma unroll
        for (int w = 0; w < BLOCK / 64; ++w) tot += red[w][threadIdx.x];
        partials[threadIdx.x * GRID + blockIdx.x] = tot;
    }
}

// 6 waves, wave k sums partials[k][0..GRID) and writes out_pairs[k].
__global__ __launch_bounds__(384) void dlrm_reduce(
        const float* __restrict__ partials, float* __restrict__ out_pairs)
{
    const int w    = threadIdx.x >> 6;
    const int lane = threadIdx.x & 63;
    const float* row = partials + w * GRID;
    float s = 0.f;
    #pragma unroll
    for (int i = 0; i < GRID / 64; ++i) s += row[lane + i * 64];
    #pragma unroll
    for (int off = 32; off > 0; off >>= 1) s += __shfl_down(s, off, 64);
    if (lane == 0) out_pairs[w] = s;
}

// ---- fallback path (ws too small): atomic version ----
__global__ void dlrm_init_pairs(float* __restrict__ out) {
    if (threadIdx.x < 6) out[(size_t)D_TOTAL + threadIdx.x] = 0.0f;
}

__global__ __launch_bounds__(BLOCK) void dlrm_interact_atomic(
        const fvec4* __restrict__ x, const fvec4* __restrict__ l0,
        const fvec4* __restrict__ l1, const fvec4* __restrict__ l2,
        fvec4* __restrict__ out_copy, float* __restrict__ out_pairs)
{
    float s[6] = {0.f, 0.f, 0.f, 0.f, 0.f, 0.f};
    const int base = blockIdx.x * CHUNK + threadIdx.x;
    #pragma unroll 4
    for (int it = 0; it < ITERS; ++it) {
        const int i = base + it * BLOCK;
        const fvec4 a = x[i], b = l0[i], c = l1[i], d = l2[i];
        __builtin_nontemporal_store(a, &out_copy[i]);
        FMA4(s[0], a, b) FMA4(s[1], a, c) FMA4(s[2], b, c)
        FMA4(s[3], a, d) FMA4(s[4], b, d) FMA4(s[5], c, d)
    }
    #pragma unroll
    for (int off = 32; off > 0; off >>= 1)
        #pragma unroll
        for (int k = 0; k < 6; ++k) s[k] += __shfl_down(s[k], off, 64);
    __shared__ float red[BLOCK / 64][6];
    const int wave = threadIdx.x >> 6, lane = threadIdx.x & 63;
    if (lane == 0)
        for (int k = 0; k < 6; ++k) red[wave][k] = s[k];
    __syncthreads();
    if (threadIdx.x < 6) {
        float tot = 0.f;
        for (int w = 0; w < BLOCK / 64; ++w) tot += red[w][threadIdx.x];
        atomicAdd(out_pairs + threadIdx.x, tot);
    }
}

extern "C" void kernel_launch(void* const* d_in, const int* in_sizes, int n_in,
                              void* d_out, int out_size, void* d_ws, size_t ws_size,
                              hipStream_t stream) {
    const fvec4* x  = (const fvec4*)d_in[0];
    const fvec4* l0 = (const fvec4*)d_in[1];
    const fvec4* l1 = (const fvec4*)d_in[2];
    const fvec4* l2 = (const fvec4*)d_in[3];
    float* out = (float*)d_out;

    if (ws_size >= (size_t)6 * GRID * sizeof(float)) {
        float* partials = (float*)d_ws;
        dlrm_interact_main<<<GRID, BLOCK, 0, stream>>>(
            x, l0, l1, l2, (fvec4*)out, partials);
        dlrm_reduce<<<1, 384, 0, stream>>>(partials, out + (size_t)D_TOTAL);
    } else {
        dlrm_init_pairs<<<1, 64, 0, stream>>>(out);
        dlrm_interact_atomic<<<GRID, BLOCK, 0, stream>>>(
            x, l0, l1, l2, (fvec4*)out, out + (size_t)D_TOTAL);
    }
}